// Round 5
// baseline (688.244 us; speedup 1.0000x reference)
//
#include <hip/hip_runtime.h>

#define N_USERC 50000
#define N_ITEMC 100000
#define NN      150000      // total nodes
#define DD      64
#define NLAYER  3
#define NNZC    2400000
#define BB      4096
#define NRID    (3*BB)      // 12288 gathered output rows
#define NBKT    147         // ceil(NN/1024) row buckets (row>>10)
#define NABLK   586         // ceil(NNZC/4096) partition blocks
#define NTILE   4688        // ceil(NN/32) 32-row tiles (fused layer kernel)

typedef unsigned short ushort_t;
typedef __attribute__((ext_vector_type(8))) short bf16x8;   // 8 bf16 = 4 VGPRs (A/B frag)
typedef __attribute__((ext_vector_type(4))) float f32x4;    // C/D frag

static __device__ __forceinline__ float bf2f(ushort_t b) {
    unsigned int u = ((unsigned int)b) << 16;
    return __uint_as_float(u);
}
static __device__ __forceinline__ ushort_t f2bf(float f) {
    unsigned int u = __float_as_uint(f);
    u = u + 0x7FFFu + ((u >> 16) & 1u);   // round-to-nearest-even
    return (ushort_t)(u >> 16);
}

// ---- dtype sniff (flag=1 if inputs are packed bf16) + zero bucket counters ----
__global__ __launch_bounds__(256) void k_sniffzb(const unsigned int* __restrict__ ue_words,
                                                 int* __restrict__ flag,
                                                 int* __restrict__ bucket_cnt) {
    int t = threadIdx.x;
    if (t < 64) {
        int cnt = 0;
        for (int i = 0; i < 4; i++) {
            unsigned int w = ue_words[t * 4 + i];
            unsigned int lo = w & 0xFFFFu;
            unsigned int ex = (lo >> 7) & 0xFF;
            if (ex >= 100 && ex <= 132) cnt++;
        }
        for (int m = 1; m < 64; m <<= 1) cnt += __shfl_xor(cnt, m, 64);
        if (t == 0) *flag = (cnt >= 128) ? 1 : 0;
    } else if (t - 64 < NBKT) {
        bucket_cnt[t - 64] = 0;
    }
}

// ---- init2: E fp32 + Eb bf16 from inputs (runs after phaseB: Eb0 aliases binned) ----
__global__ __launch_bounds__(256) void k_init2(const void* __restrict__ ue,
                                               const void* __restrict__ ie,
                                               const int* __restrict__ flag,
                                               float* __restrict__ E,
                                               ushort_t* __restrict__ Eb0) {
    int idx = blockIdx.x * 256 + threadIdx.x;           // over NN*64
    if (idx >= NN * DD) return;
    int row = idx >> 6;
    bool isU = row < N_USERC;
    int si = isU ? idx : idx - N_USERC * DD;
    float v;
    if (*flag) {
        v = bf2f(isU ? ((const ushort_t*)ue)[si] : ((const ushort_t*)ie)[si]);
    } else {
        v = isU ? ((const float*)ue)[si] : ((const float*)ie)[si];
    }
    E[idx] = v;
    Eb0[idx] = f2bf(v);
}

// ---- W prep: pack W1,W2 into pre-swizzled bf16 B-fragments + bias sums ----
// Wfrag layout: [l][s(4)][jt(4)][lane(64)][i(8)] ushort.
// B-frag (16x16x32): col = jt*16 + (lane&15); k = 32*(s&1) + 8*(lane>>4) + i;
// matrix = W1 for s<2, W2 for s>=2. A-side uses the identical k map, so any
// HW k-permutation cancels (same map both operands).
__global__ __launch_bounds__(256) void k_wprep(const void* __restrict__ W1,
                                               const void* __restrict__ W2,
                                               const void* __restrict__ b1,
                                               const void* __restrict__ b2,
                                               const int* __restrict__ flag,
                                               ushort_t* __restrict__ Wfrag,
                                               float* __restrict__ bsum) {
    int idx = blockIdx.x * 256 + threadIdx.x;
    int isbf = *flag;
    if (idx < NLAYER * 4 * 4 * 64 * 8) {
        int i    = idx & 7;
        int lane = (idx >> 3) & 63;
        int jt   = (idx >> 9) & 3;
        int s    = (idx >> 11) & 3;
        int l    = idx >> 13;
        int kfull = 32 * (s & 1) + 8 * (lane >> 4) + i;
        int col   = jt * 16 + (lane & 15);
        const void* W = (s < 2) ? W1 : W2;
        size_t off = (size_t)l * 4096 + (size_t)kfull * 64 + col;
        float v = isbf ? bf2f(((const ushort_t*)W)[off]) : ((const float*)W)[off];
        Wfrag[idx] = f2bf(v);
    } else {
        int r = idx - NLAYER * 4 * 4 * 64 * 8;
        if (r < NLAYER * 64) {
            float v1 = isbf ? bf2f(((const ushort_t*)b1)[r]) : ((const float*)b1)[r];
            float v2 = isbf ? bf2f(((const ushort_t*)b2)[r]) : ((const float*)b2)[r];
            bsum[r] = v1 + v2;
        }
    }
}

// ---- bucket histogram: 147 buckets of 1024 rows ----
__global__ __launch_bounds__(256) void k_bhist(const int* __restrict__ rows,
                                               int* __restrict__ bucket_cnt) {
    __shared__ int h[NBKT];
    int t = threadIdx.x;
    if (t < NBKT) h[t] = 0;
    __syncthreads();
    int e0 = blockIdx.x * 4096;
#pragma unroll
    for (int i = 0; i < 16; i++) {
        int e = e0 + t + i * 256;
        if (e < NNZC) atomicAdd(&h[rows[e] >> 10], 1);
    }
    __syncthreads();
    if (t < NBKT && h[t]) atomicAdd(&bucket_cnt[t], h[t]);
}

// ---- exclusive scan of 147 bucket counts; seed bases/cursors ----
__global__ __launch_bounds__(256) void k_bscan(const int* __restrict__ bucket_cnt,
                                               int* __restrict__ gbase,
                                               int* __restrict__ gcursor,
                                               int* __restrict__ row_ptr) {
    __shared__ int s[256];
    int t = threadIdx.x;
    int v = (t < NBKT) ? bucket_cnt[t] : 0;
    s[t] = v; __syncthreads();
    for (int off = 1; off < 256; off <<= 1) {
        int x = (t >= off) ? s[t - off] : 0;
        __syncthreads();
        s[t] += x;
        __syncthreads();
    }
    if (t < NBKT) { int ex = s[t] - v; gbase[t] = ex; gcursor[t] = ex; }
    if (t == 0) { gbase[NBKT] = NNZC; row_ptr[NN] = NNZC; }
}

// ---- phase A: partition edges into 147 row-buckets ----
__global__ __launch_bounds__(256) void k_phaseA(const int* __restrict__ rows,
                                                const int* __restrict__ cols,
                                                const void* __restrict__ vals,
                                                const int* __restrict__ flag,
                                                int* __restrict__ gcursor,
                                                int2* __restrict__ binned) {
    __shared__ int hist[NBKT], base_[NBKT], lcur[NBKT];
    int t = threadIdx.x;
    int e0 = blockIdx.x * 4096;
    if (t < NBKT) { hist[t] = 0; lcur[t] = 0; }
    __syncthreads();
    int myrow[16];
#pragma unroll
    for (int i = 0; i < 16; i++) {
        int e = e0 + t + i * 256;
        int r = -1;
        if (e < NNZC) { r = rows[e]; atomicAdd(&hist[r >> 10], 1); }
        myrow[i] = r;
    }
    __syncthreads();
    if (t < NBKT && hist[t] > 0) base_[t] = atomicAdd(&gcursor[t], hist[t]);
    __syncthreads();
    int isbf = *flag;
#pragma unroll
    for (int i = 0; i < 16; i++) {
        int e = e0 + t + i * 256;
        if (e < NNZC) {
            int r = myrow[i];
            int bkt = r >> 10;
            int off = atomicAdd(&lcur[bkt], 1);
            int pos = base_[bkt] + off;
            int c = cols[e];
            float v = isbf ? bf2f(((const ushort_t*)vals)[e]) : ((const float*)vals)[e];
            binned[pos] = make_int2(((r & 1023) << 18) | c, __float_as_int(v));
        }
    }
}

// ---- phase B: one block per bucket; exact CSR slice via LDS hist+scan+cursor ----
__global__ __launch_bounds__(256) void k_phaseB(const int* __restrict__ gbase,
                                                const int2* __restrict__ binned,
                                                int2* __restrict__ ep,
                                                int* __restrict__ row_ptr) {
    __shared__ int rc[1024];
    __shared__ int rofs[1024];
    int b = blockIdx.x, t = threadIdx.x;
    int s = gbase[b], e = gbase[b + 1];
    for (int i = t; i < 1024; i += 256) rc[i] = 0;
    __syncthreads();
    for (int i = s + t; i < e; i += 256)
        atomicAdd(&rc[binned[i].x >> 18], 1);
    __syncthreads();
    for (int i = t; i < 1024; i += 256) rofs[i] = rc[i];
    __syncthreads();
    for (int off = 1; off < 1024; off <<= 1) {
        int v[4];
#pragma unroll
        for (int j = 0; j < 4; j++) {
            int idx = t + j * 256;
            v[j] = (idx >= off) ? rc[idx - off] : 0;
        }
        __syncthreads();
#pragma unroll
        for (int j = 0; j < 4; j++) rc[t + j * 256] += v[j];
        __syncthreads();
    }
    for (int i = t; i < 1024; i += 256) {
        int ex = rc[i] - rofs[i];
        int gr = b * 1024 + i;
        if (gr < NN) row_ptr[gr] = s + ex;
        rofs[i] = ex;
    }
    __syncthreads();
    for (int i = s + t; i < e; i += 256) {
        int2 en = binned[i];
        int rl = en.x >> 18;
        int c  = en.x & 0x3FFFF;
        int off = atomicAdd(&rofs[rl], 1);
        ep[s + off] = make_int2(c, en.y);
    }
}

// ---- fused layer v2: block = 32 rows; wave owns rows wv*8..wv*8+7.
// Phase 1 pipelines 4 rows CONCURRENTLY (2 passes): all 4 rows' ep loads
// issue, then all 8 gathers (4 rows x 2 slots), then FMAs — 8 outstanding
// 128B gathers/wave vs the serial version's 2 (round-3 lesson: cross-row MLP
// is the only pipeline available at mean degree 16). Row bounds via one
// 9-wide load + readlane -> uniform scalars -> s_cbranch row-activity.
// Phase 2: mdense MFMA from LDS (LE never touches HBM). Eb ping-pong
// double-buffered across layers -> no cross-block race. ----
__global__ __launch_bounds__(256) void k_layer(const int* __restrict__ row_ptr,
                                               const int2* __restrict__ ep,
                                               const ushort_t* __restrict__ Eb_in,
                                               float* __restrict__ E,
                                               ushort_t* __restrict__ Eb_out,
                                               const ushort_t* __restrict__ Wfrag,
                                               const float* __restrict__ bsum,
                                               int layer) {
    __shared__ float sLE[32][68];
    __shared__ float sE [32][68];

    int t    = threadIdx.x;
    int wv   = t >> 6;
    int lane = t & 63;
    int oct  = lane >> 3;
    int d8   = (lane & 7) * 8;
    int hl   = lane >> 4;
    int l16  = lane & 15;
    int r0   = blockIdx.x << 5;

    // ---- E-row prefetch into LDS (overlaps with spmm gathers below) ----
    {
        int lr = t >> 3;
        int dm = (t & 7) * 8;
        int gr = r0 + lr;
        float4 va = make_float4(0.f, 0.f, 0.f, 0.f), vb = va;
        if (gr < NN) {
            const float4* p = (const float4*)(E + (size_t)gr * DD + dm);
            va = p[0]; vb = p[1];
        }
        *(float4*)&sE[lr][dm]     = va;
        *(float4*)&sE[lr][dm + 4] = vb;
    }

    // ---- row bounds: one 9-wide load, then readlane (uniform scalars) ----
    int base = r0 + wv * 8;
    int rp = 0;
    if (lane < 9) rp = row_ptr[base + lane];    // padded alloc: safe past NN

#pragma unroll
    for (int pass = 0; pass < 2; pass++) {
        int j0 = pass * 4;
        int s0 = __builtin_amdgcn_readlane(rp, j0 + 0);
        int s1 = __builtin_amdgcn_readlane(rp, j0 + 1);
        int s2 = __builtin_amdgcn_readlane(rp, j0 + 2);
        int s3 = __builtin_amdgcn_readlane(rp, j0 + 3);
        int e0 = s1, e1 = s2, e2 = s3;
        int e3 = __builtin_amdgcn_readlane(rp, j0 + 4);
        // deactivate rows past NN (padded row_ptr holds garbage there)
        if (base + j0 + 0 >= NN) { s0 = 0; e0 = 0; }
        if (base + j0 + 1 >= NN) { s1 = 0; e1 = 0; }
        if (base + j0 + 2 >= NN) { s2 = 0; e2 = 0; }
        if (base + j0 + 3 >= NN) { s3 = 0; e3 = 0; }

        float ac0[8], ac1[8], ac2[8], ac3[8];
#pragma unroll
        for (int k = 0; k < 8; k++) { ac0[k] = 0.f; ac1[k] = 0.f; ac2[k] = 0.f; ac3[k] = 0.f; }
        int i0 = s0, i1 = s1, i2 = s2, i3 = s3;

        while ((i0 < e0) | (i1 < e1) | (i2 < e2) | (i3 < e3)) {
            int2 pv0[2], pv1[2], pv2[2], pv3[2];
            uint4 q0[2], q1[2], q2[2], q3[2];
            // stage 1: ep loads for all active rows (independent)
#pragma unroll
            for (int v = 0; v < 2; v++) {
                if (i0 < e0) { int ix = i0 + v * 8 + oct; pv0[v] = ep[(ix < e0) ? ix : s0]; }
                if (i1 < e1) { int ix = i1 + v * 8 + oct; pv1[v] = ep[(ix < e1) ? ix : s1]; }
                if (i2 < e2) { int ix = i2 + v * 8 + oct; pv2[v] = ep[(ix < e2) ? ix : s2]; }
                if (i3 < e3) { int ix = i3 + v * 8 + oct; pv3[v] = ep[(ix < e3) ? ix : s3]; }
            }
            // stage 2: gathers (each depends only on its pv; up to 8 in flight)
#pragma unroll
            for (int v = 0; v < 2; v++) {
                if (i0 < e0) q0[v] = *(const uint4*)(Eb_in + ((size_t)(unsigned)pv0[v].x << 6) + d8);
                if (i1 < e1) q1[v] = *(const uint4*)(Eb_in + ((size_t)(unsigned)pv1[v].x << 6) + d8);
                if (i2 < e2) q2[v] = *(const uint4*)(Eb_in + ((size_t)(unsigned)pv2[v].x << 6) + d8);
                if (i3 < e3) q3[v] = *(const uint4*)(Eb_in + ((size_t)(unsigned)pv3[v].x << 6) + d8);
            }
            // stage 3: FMA + advance
#pragma unroll
            for (int v = 0; v < 2; v++) {
                if (i0 < e0) {
                    float w = (i0 + v * 8 + oct < e0) ? __int_as_float(pv0[v].y) : 0.f;
                    ac0[0] = fmaf(w, __uint_as_float(q0[v].x << 16),         ac0[0]);
                    ac0[1] = fmaf(w, __uint_as_float(q0[v].x & 0xffff0000u), ac0[1]);
                    ac0[2] = fmaf(w, __uint_as_float(q0[v].y << 16),         ac0[2]);
                    ac0[3] = fmaf(w, __uint_as_float(q0[v].y & 0xffff0000u), ac0[3]);
                    ac0[4] = fmaf(w, __uint_as_float(q0[v].z << 16),         ac0[4]);
                    ac0[5] = fmaf(w, __uint_as_float(q0[v].z & 0xffff0000u), ac0[5]);
                    ac0[6] = fmaf(w, __uint_as_float(q0[v].w << 16),         ac0[6]);
                    ac0[7] = fmaf(w, __uint_as_float(q0[v].w & 0xffff0000u), ac0[7]);
                }
                if (i1 < e1) {
                    float w = (i1 + v * 8 + oct < e1) ? __int_as_float(pv1[v].y) : 0.f;
                    ac1[0] = fmaf(w, __uint_as_float(q1[v].x << 16),         ac1[0]);
                    ac1[1] = fmaf(w, __uint_as_float(q1[v].x & 0xffff0000u), ac1[1]);
                    ac1[2] = fmaf(w, __uint_as_float(q1[v].y << 16),         ac1[2]);
                    ac1[3] = fmaf(w, __uint_as_float(q1[v].y & 0xffff0000u), ac1[3]);
                    ac1[4] = fmaf(w, __uint_as_float(q1[v].z << 16),         ac1[4]);
                    ac1[5] = fmaf(w, __uint_as_float(q1[v].z & 0xffff0000u), ac1[5]);
                    ac1[6] = fmaf(w, __uint_as_float(q1[v].w << 16),         ac1[6]);
                    ac1[7] = fmaf(w, __uint_as_float(q1[v].w & 0xffff0000u), ac1[7]);
                }
                if (i2 < e2) {
                    float w = (i2 + v * 8 + oct < e2) ? __int_as_float(pv2[v].y) : 0.f;
                    ac2[0] = fmaf(w, __uint_as_float(q2[v].x << 16),         ac2[0]);
                    ac2[1] = fmaf(w, __uint_as_float(q2[v].x & 0xffff0000u), ac2[1]);
                    ac2[2] = fmaf(w, __uint_as_float(q2[v].y << 16),         ac2[2]);
                    ac2[3] = fmaf(w, __uint_as_float(q2[v].y & 0xffff0000u), ac2[3]);
                    ac2[4] = fmaf(w, __uint_as_float(q2[v].z << 16),         ac2[4]);
                    ac2[5] = fmaf(w, __uint_as_float(q2[v].z & 0xffff0000u), ac2[5]);
                    ac2[6] = fmaf(w, __uint_as_float(q2[v].w << 16),         ac2[6]);
                    ac2[7] = fmaf(w, __uint_as_float(q2[v].w & 0xffff0000u), ac2[7]);
                }
                if (i3 < e3) {
                    float w = (i3 + v * 8 + oct < e3) ? __int_as_float(pv3[v].y) : 0.f;
                    ac3[0] = fmaf(w, __uint_as_float(q3[v].x << 16),         ac3[0]);
                    ac3[1] = fmaf(w, __uint_as_float(q3[v].x & 0xffff0000u), ac3[1]);
                    ac3[2] = fmaf(w, __uint_as_float(q3[v].y << 16),         ac3[2]);
                    ac3[3] = fmaf(w, __uint_as_float(q3[v].y & 0xffff0000u), ac3[3]);
                    ac3[4] = fmaf(w, __uint_as_float(q3[v].z << 16),         ac3[4]);
                    ac3[5] = fmaf(w, __uint_as_float(q3[v].z & 0xffff0000u), ac3[5]);
                    ac3[6] = fmaf(w, __uint_as_float(q3[v].w << 16),         ac3[6]);
                    ac3[7] = fmaf(w, __uint_as_float(q3[v].w & 0xffff0000u), ac3[7]);
                }
            }
            if (i0 < e0) i0 += 16;
            if (i1 < e1) i1 += 16;
            if (i2 < e2) i2 += 16;
            if (i3 < e3) i3 += 16;
        }

        // fold octs (butterfly over lane bits 3,4,5) and store LE rows to LDS
#pragma unroll
        for (int m = 8; m < 64; m <<= 1)
#pragma unroll
            for (int k = 0; k < 8; k++) {
                ac0[k] += __shfl_xor(ac0[k], m, 64);
                ac1[k] += __shfl_xor(ac1[k], m, 64);
                ac2[k] += __shfl_xor(ac2[k], m, 64);
                ac3[k] += __shfl_xor(ac3[k], m, 64);
            }
        if (oct == 0) {
            int lr = wv * 8 + j0;
            *(float4*)&sLE[lr + 0][d8]     = make_float4(ac0[0], ac0[1], ac0[2], ac0[3]);
            *(float4*)&sLE[lr + 0][d8 + 4] = make_float4(ac0[4], ac0[5], ac0[6], ac0[7]);
            *(float4*)&sLE[lr + 1][d8]     = make_float4(ac1[0], ac1[1], ac1[2], ac1[3]);
            *(float4*)&sLE[lr + 1][d8 + 4] = make_float4(ac1[4], ac1[5], ac1[6], ac1[7]);
            *(float4*)&sLE[lr + 2][d8]     = make_float4(ac2[0], ac2[1], ac2[2], ac2[3]);
            *(float4*)&sLE[lr + 2][d8 + 4] = make_float4(ac2[4], ac2[5], ac2[6], ac2[7]);
            *(float4*)&sLE[lr + 3][d8]     = make_float4(ac3[0], ac3[1], ac3[2], ac3[3]);
            *(float4*)&sLE[lr + 3][d8 + 4] = make_float4(ac3[4], ac3[5], ac3[6], ac3[7]);
        }
    }
    __syncthreads();

    // ---- phase 2: dense. wave -> (rt = wv&1, jts = {2*(wv>>1), 2*(wv>>1)+1}) ----
    int rt = wv & 1;
    int j0w = wv >> 1;                      // jt pair index
    int jtA = 2 * j0w, jtB = 2 * j0w + 1;
    const uint4* wb = (const uint4*)(Wfrag + (size_t)layer * 8192);
    float bsA = bsum[layer * 64 + jtA * 16 + l16];
    float bsB = bsum[layer * 64 + jtB * 16 + l16];

    f32x4 accA = (f32x4){0.f, 0.f, 0.f, 0.f};
    f32x4 accB = (f32x4){0.f, 0.f, 0.f, 0.f};
    int lrow = rt * 16 + l16;

#pragma unroll
    for (int sh = 0; sh < 2; sh++) {
        bf16x8 w1a, w1b, w2a, w2b;
        {
            uint4 qa = wb[(sh * 4 + jtA) * 64 + lane];
            uint4 qb = wb[(sh * 4 + jtB) * 64 + lane];
            uint4 qc = wb[((2 + sh) * 4 + jtA) * 64 + lane];
            uint4 qd = wb[((2 + sh) * 4 + jtB) * 64 + lane];
            __builtin_memcpy(&w1a, &qa, 16);
            __builtin_memcpy(&w1b, &qb, 16);
            __builtin_memcpy(&w2a, &qc, 16);
            __builtin_memcpy(&w2b, &qd, 16);
        }
        const float* pl = &sLE[lrow][sh * 32 + hl * 8];
        const float* pe = &sE [lrow][sh * 32 + hl * 8];
        float4 l0 = *(const float4*)pl, l1 = *(const float4*)(pl + 4);
        float4 e0 = *(const float4*)pe, e1 = *(const float4*)(pe + 4);
        float le[8] = {l0.x, l0.y, l0.z, l0.w, l1.x, l1.y, l1.z, l1.w};
        float ee[8] = {e0.x, e0.y, e0.z, e0.w, e1.x, e1.y, e1.z, e1.w};
        unsigned int u1h[4], u1l[4], u2h[4], u2l[4];
#pragma unroll
        for (int d = 0; d < 4; d++) {
            float s0 = le[2*d]   + ee[2*d];
            float s1 = le[2*d+1] + ee[2*d+1];
            float m0 = le[2*d]   * ee[2*d];
            float m1 = le[2*d+1] * ee[2*d+1];
            asm("v_cvt_pk_bf16_f32 %0, %1, %2" : "=v"(u1h[d]) : "v"(s0), "v"(s1));
            asm("v_cvt_pk_bf16_f32 %0, %1, %2" : "=v"(u2h[d]) : "v"(m0), "v"(m1));
            float s0r = s0 - __uint_as_float(u1h[d] << 16);
            float s1r = s1 - __uint_as_float(u1h[d] & 0xffff0000u);
            float m0r = m0 - __uint_as_float(u2h[d] << 16);
            float m1r = m1 - __uint_as_float(u2h[d] & 0xffff0000u);
            asm("v_cvt_pk_bf16_f32 %0, %1, %2" : "=v"(u1l[d]) : "v"(s0r), "v"(s1r));
            asm("v_cvt_pk_bf16_f32 %0, %1, %2" : "=v"(u2l[d]) : "v"(m0r), "v"(m1r));
        }
        bf16x8 p1h, p1l, p2h, p2l;
        __builtin_memcpy(&p1h, u1h, 16);
        __builtin_memcpy(&p1l, u1l, 16);
        __builtin_memcpy(&p2h, u2h, 16);
        __builtin_memcpy(&p2l, u2l, 16);

        accA = __builtin_amdgcn_mfma_f32_16x16x32_bf16(p1h, w1a, accA, 0, 0, 0);
        accA = __builtin_amdgcn_mfma_f32_16x16x32_bf16(p1l, w1a, accA, 0, 0, 0);
        accA = __builtin_amdgcn_mfma_f32_16x16x32_bf16(p2h, w2a, accA, 0, 0, 0);
        accA = __builtin_amdgcn_mfma_f32_16x16x32_bf16(p2l, w2a, accA, 0, 0, 0);
        accB = __builtin_amdgcn_mfma_f32_16x16x32_bf16(p1h, w1b, accB, 0, 0, 0);
        accB = __builtin_amdgcn_mfma_f32_16x16x32_bf16(p1l, w1b, accB, 0, 0, 0);
        accB = __builtin_amdgcn_mfma_f32_16x16x32_bf16(p2h, w2b, accB, 0, 0, 0);
        accB = __builtin_amdgcn_mfma_f32_16x16x32_bf16(p2l, w2b, accB, 0, 0, 0);
    }

    // epilogue: bias + leaky relu; C/D layout col=lane&15, row=(lane>>4)*4+g
#pragma unroll
    for (int g = 0; g < 4; g++) {
        int r = r0 + rt * 16 + hl * 4 + g;
        if (r < NN) {
            float hA = accA[g] + bsA; hA = (hA >= 0.f) ? hA : 0.2f * hA;
            float hB = accB[g] + bsB; hB = (hB >= 0.f) ? hB : 0.2f * hB;
            E[(size_t)r * DD + jtA * 16 + l16] = hA;
            E[(size_t)r * DD + jtB * 16 + l16] = hB;
            Eb_out[(size_t)r * DD + jtA * 16 + l16] = f2bf(hA);
            Eb_out[(size_t)r * DD + jtB * 16 + l16] = f2bf(hB);
        }
    }
}

static __device__ __forceinline__ int rid_to_node(int rid,
                                                  const int* users, const int* pos, const int* neg) {
    if (rid < BB)      return users[rid] - 1;
    if (rid < 2 * BB)  return N_USERC + pos[rid - BB] - 1;
    return N_USERC + neg[rid - 2 * BB] - 1;
}

// ---- slice 0 of output: raw initial embedding (fp32) of gathered rows ----
__global__ __launch_bounds__(256) void k_outslice0(const float* __restrict__ E,
                                                   const int* __restrict__ users,
                                                   const int* __restrict__ pos,
                                                   const int* __restrict__ neg,
                                                   float* __restrict__ out) {
    int rid  = blockIdx.x * 4 + (threadIdx.x >> 6);
    int lane = threadIdx.x & 63;
    if (rid >= NRID) return;
    int node = rid_to_node(rid, users, pos, neg);
    out[(size_t)rid * 256 + lane] = E[(size_t)node * DD + lane];
}

// ---- slice l+1: normalized current E of gathered rows (fp32) ----
__global__ __launch_bounds__(256) void k_outnorm(const float* __restrict__ E,
                                                 const int* __restrict__ users,
                                                 const int* __restrict__ pos,
                                                 const int* __restrict__ neg,
                                                 float* __restrict__ out,
                                                 int cbase) {
    int rid  = blockIdx.x * 4 + (threadIdx.x >> 6);
    int lane = threadIdx.x & 63;
    if (rid >= NRID) return;
    int node = rid_to_node(rid, users, pos, neg);
    float v = E[(size_t)node * DD + lane];
    float p2 = v * v;
    for (int m = 1; m < 64; m <<= 1) p2 += __shfl_xor(p2, m, 64);
    float nr = fmaxf(sqrtf(p2), 1e-12f);
    out[(size_t)rid * 256 + cbase + lane] = v / nr;
}

extern "C" void kernel_launch(void* const* d_in, const int* in_sizes, int n_in,
                              void* d_out, int out_size, void* d_ws, size_t ws_size,
                              hipStream_t stream) {
    const void* ue   = d_in[0];
    const void* ie   = d_in[1];
    const void* ev   = d_in[2];
    const void* W1   = d_in[3];
    const void* b1   = d_in[4];
    const void* W2   = d_in[5];
    const void* b2   = d_in[6];
    const int*  ei   = (const int*)d_in[7];
    const int*  usr  = (const int*)d_in[8];
    const int*  posi = (const int*)d_in[9];
    const int*  negi = (const int*)d_in[10];
    float*      out  = (float*)d_out;

    const int* rows = ei;
    const int* cols = ei + NNZC;

    // workspace carve — ~116 MB (Eb0 aliases binned: binned dead after phaseB;
    // Eb1 aliases the old LE slot: LE never goes to HBM in the fused design)
    char* w = (char*)d_ws;
    float*  E         = (float*)w;  w += (size_t)NN * DD * 4;    // 38.4 MB
    ushort_t* Eb1     = (ushort_t*)w; w += (size_t)NN * DD * 4;  // 19.2 MB used of 38.4
    int2*   binned    = (int2*)w;   w += (size_t)NNZC * 8;       // 19.2 MB
    ushort_t* Eb0     = (ushort_t*)binned;                       // alias (19.2 MB need)
    int2*   ep        = (int2*)w;   w += (size_t)NNZC * 8;       // 19.2 MB
    int*    row_ptr   = (int*)w;    w += 600320;                 // NN+1 ints padded
    int*    gbase     = (int*)w;    w += 1024;
    int*    gcursor   = (int*)w;    w += 1024;
    int*    bucket_cnt= (int*)w;    w += 1024;
    int*    flag      = (int*)w;    w += 256;
    ushort_t* Wfrag   = (ushort_t*)w; w += 49152;                // 3*4*4*64*8 bf16
    float*  bsum      = (float*)w;  w += 768;                    // 3*64 fp32

    k_sniffzb<<<1, 256, 0, stream>>>((const unsigned int*)ue, flag, bucket_cnt);
    k_wprep<<<97, 256, 0, stream>>>(W1, W2, b1, b2, flag, Wfrag, bsum);
    k_bhist<<<NABLK, 256, 0, stream>>>(rows, bucket_cnt);
    k_bscan<<<1, 256, 0, stream>>>(bucket_cnt, gbase, gcursor, row_ptr);
    k_phaseA<<<NABLK, 256, 0, stream>>>(rows, cols, ev, flag, gcursor, binned);
    k_phaseB<<<NBKT, 256, 0, stream>>>(gbase, binned, ep, row_ptr);
    k_init2<<<37500, 256, 0, stream>>>(ue, ie, flag, E, Eb0);   // after phaseB: binned dead

    k_outslice0<<<3072, 256, 0, stream>>>(E, usr, posi, negi, out);

    for (int l = 0; l < NLAYER; l++) {
        const ushort_t* ebi = (l & 1) ? Eb1 : Eb0;
        ushort_t*       ebo = (l & 1) ? Eb0 : Eb1;
        k_layer<<<NTILE, 256, 0, stream>>>(row_ptr, ep, ebi, E, ebo, Wfrag, bsum, l);
        k_outnorm<<<3072, 256, 0, stream>>>(E, usr, posi, negi, out, 64 * (l + 1));
    }
}

// Round 6
// 450.280 us; speedup vs baseline: 1.5285x; 1.5285x over previous
//
#include <hip/hip_runtime.h>

#define N_USERC 50000
#define N_ITEMC 100000
#define NN      150000      // total nodes
#define DD      64
#define NLAYER  3
#define NNZC    2400000
#define BB      4096
#define NRID    (3*BB)      // 12288 gathered output rows
#define NBKT    147         // ceil(NN/1024) row buckets (row>>10)
#define NABLK   586         // ceil(NNZC/4096) partition blocks
#define NTILE   4688        // ceil(NN/32) 32-row tiles (fused layer kernel)
#define ELLW    32          // ELL width: P(deg>32 | Poisson(16)) ~ 1.4e-4
#define ELLROWS 150528      // NBKT*1024 (phaseB writes padded row space)
#define OVCAP   32768       // overflow COO capacity (expected ~40 entries)
#define NZBLK   9408        // ELLROWS*32*8 / 16 / 256 zero-fill blocks

typedef unsigned short ushort_t;
typedef __attribute__((ext_vector_type(8))) short bf16x8;   // 8 bf16 = 4 VGPRs (A/B frag)
typedef __attribute__((ext_vector_type(4))) float f32x4;    // C/D frag

static __device__ __forceinline__ float bf2f(ushort_t b) {
    unsigned int u = ((unsigned int)b) << 16;
    return __uint_as_float(u);
}
static __device__ __forceinline__ ushort_t f2bf(float f) {
    unsigned int u = __float_as_uint(f);
    u = u + 0x7FFFu + ((u >> 16) & 1u);   // round-to-nearest-even
    return (ushort_t)(u >> 16);
}

// ---- dtype sniff (flag=1 if inputs are packed bf16) + zero bucket counters ----
__global__ __launch_bounds__(256) void k_sniffzb(const unsigned int* __restrict__ ue_words,
                                                 int* __restrict__ flag,
                                                 int* __restrict__ bucket_cnt) {
    int t = threadIdx.x;
    if (t < 64) {
        int cnt = 0;
        for (int i = 0; i < 4; i++) {
            unsigned int w = ue_words[t * 4 + i];
            unsigned int lo = w & 0xFFFFu;
            unsigned int ex = (lo >> 7) & 0xFF;
            if (ex >= 100 && ex <= 132) cnt++;
        }
        for (int m = 1; m < 64; m <<= 1) cnt += __shfl_xor(cnt, m, 64);
        if (t == 0) *flag = (cnt >= 128) ? 1 : 0;
    } else if (t - 64 < NBKT) {
        bucket_cnt[t - 64] = 0;
    }
}

// ---- zero ELL (dummy slots must read as col=0,val=0) + overflow counter ----
__global__ __launch_bounds__(256) void k_zell(int4* __restrict__ ell4,
                                              int* __restrict__ ovcnt) {
    int idx = blockIdx.x * 256 + threadIdx.x;
    ell4[idx] = make_int4(0, 0, 0, 0);
    if (idx == 0) *ovcnt = 0;
}

// ---- init2: E fp32 + Eb bf16 from inputs (runs after phaseB: Eb0 aliases binned) ----
__global__ __launch_bounds__(256) void k_init2(const void* __restrict__ ue,
                                               const void* __restrict__ ie,
                                               const int* __restrict__ flag,
                                               float* __restrict__ E,
                                               ushort_t* __restrict__ Eb0) {
    int idx = blockIdx.x * 256 + threadIdx.x;           // over NN*64
    if (idx >= NN * DD) return;
    int row = idx >> 6;
    bool isU = row < N_USERC;
    int si = isU ? idx : idx - N_USERC * DD;
    float v;
    if (*flag) {
        v = bf2f(isU ? ((const ushort_t*)ue)[si] : ((const ushort_t*)ie)[si]);
    } else {
        v = isU ? ((const float*)ue)[si] : ((const float*)ie)[si];
    }
    E[idx] = v;
    Eb0[idx] = f2bf(v);
}

// ---- W prep: pack W1,W2 into pre-swizzled bf16 B-fragments + bias sums ----
// Wfrag layout: [l][s(4)][jt(4)][lane(64)][i(8)] ushort.
// B-frag (16x16x32): col = jt*16 + (lane&15); k = 32*(s&1) + 8*(lane>>4) + i;
// matrix = W1 for s<2, W2 for s>=2. A-side uses the identical k map, so any
// HW k-permutation cancels (same map both operands).
__global__ __launch_bounds__(256) void k_wprep(const void* __restrict__ W1,
                                               const void* __restrict__ W2,
                                               const void* __restrict__ b1,
                                               const void* __restrict__ b2,
                                               const int* __restrict__ flag,
                                               ushort_t* __restrict__ Wfrag,
                                               float* __restrict__ bsum) {
    int idx = blockIdx.x * 256 + threadIdx.x;
    int isbf = *flag;
    if (idx < NLAYER * 4 * 4 * 64 * 8) {
        int i    = idx & 7;
        int lane = (idx >> 3) & 63;
        int jt   = (idx >> 9) & 3;
        int s    = (idx >> 11) & 3;
        int l    = idx >> 13;
        int kfull = 32 * (s & 1) + 8 * (lane >> 4) + i;
        int col   = jt * 16 + (lane & 15);
        const void* W = (s < 2) ? W1 : W2;
        size_t off = (size_t)l * 4096 + (size_t)kfull * 64 + col;
        float v = isbf ? bf2f(((const ushort_t*)W)[off]) : ((const float*)W)[off];
        Wfrag[idx] = f2bf(v);
    } else {
        int r = idx - NLAYER * 4 * 4 * 64 * 8;
        if (r < NLAYER * 64) {
            float v1 = isbf ? bf2f(((const ushort_t*)b1)[r]) : ((const float*)b1)[r];
            float v2 = isbf ? bf2f(((const ushort_t*)b2)[r]) : ((const float*)b2)[r];
            bsum[r] = v1 + v2;
        }
    }
}

// ---- bucket histogram: 147 buckets of 1024 rows ----
__global__ __launch_bounds__(256) void k_bhist(const int* __restrict__ rows,
                                               int* __restrict__ bucket_cnt) {
    __shared__ int h[NBKT];
    int t = threadIdx.x;
    if (t < NBKT) h[t] = 0;
    __syncthreads();
    int e0 = blockIdx.x * 4096;
#pragma unroll
    for (int i = 0; i < 16; i++) {
        int e = e0 + t + i * 256;
        if (e < NNZC) atomicAdd(&h[rows[e] >> 10], 1);
    }
    __syncthreads();
    if (t < NBKT && h[t]) atomicAdd(&bucket_cnt[t], h[t]);
}

// ---- exclusive scan of 147 bucket counts; seed bases/cursors ----
__global__ __launch_bounds__(256) void k_bscan(const int* __restrict__ bucket_cnt,
                                               int* __restrict__ gbase,
                                               int* __restrict__ gcursor) {
    __shared__ int s[256];
    int t = threadIdx.x;
    int v = (t < NBKT) ? bucket_cnt[t] : 0;
    s[t] = v; __syncthreads();
    for (int off = 1; off < 256; off <<= 1) {
        int x = (t >= off) ? s[t - off] : 0;
        __syncthreads();
        s[t] += x;
        __syncthreads();
    }
    if (t < NBKT) { int ex = s[t] - v; gbase[t] = ex; gcursor[t] = ex; }
    if (t == 0) { gbase[NBKT] = NNZC; }
}

// ---- phase A: partition edges into 147 row-buckets ----
__global__ __launch_bounds__(256) void k_phaseA(const int* __restrict__ rows,
                                                const int* __restrict__ cols,
                                                const void* __restrict__ vals,
                                                const int* __restrict__ flag,
                                                int* __restrict__ gcursor,
                                                int2* __restrict__ binned) {
    __shared__ int hist[NBKT], base_[NBKT], lcur[NBKT];
    int t = threadIdx.x;
    int e0 = blockIdx.x * 4096;
    if (t < NBKT) { hist[t] = 0; lcur[t] = 0; }
    __syncthreads();
    int myrow[16];
#pragma unroll
    for (int i = 0; i < 16; i++) {
        int e = e0 + t + i * 256;
        int r = -1;
        if (e < NNZC) { r = rows[e]; atomicAdd(&hist[r >> 10], 1); }
        myrow[i] = r;
    }
    __syncthreads();
    if (t < NBKT && hist[t] > 0) base_[t] = atomicAdd(&gcursor[t], hist[t]);
    __syncthreads();
    int isbf = *flag;
#pragma unroll
    for (int i = 0; i < 16; i++) {
        int e = e0 + t + i * 256;
        if (e < NNZC) {
            int r = myrow[i];
            int bkt = r >> 10;
            int off = atomicAdd(&lcur[bkt], 1);
            int pos = base_[bkt] + off;
            int c = cols[e];
            float v = isbf ? bf2f(((const ushort_t*)vals)[e]) : ((const float*)vals)[e];
            binned[pos] = make_int2(((r & 1023) << 18) | c, __float_as_int(v));
        }
    }
}

// ---- phase B (ELL): one block per bucket; per-row LDS cursors scatter edges
// into ell[row*32 + slot]; slot>=32 spills to overflow COO. No scan, no
// row_ptr — k_layer reads fixed-width rows with zero-padded dummy slots. ----
__global__ __launch_bounds__(256) void k_phaseB(const int* __restrict__ gbase,
                                                const int2* __restrict__ binned,
                                                int2* __restrict__ ell,
                                                int4* __restrict__ ovbuf,
                                                int* __restrict__ ovcnt) {
    __shared__ int rcur[1024];
    int b = blockIdx.x, t = threadIdx.x;
    int s = gbase[b], e = gbase[b + 1];
    for (int i = t; i < 1024; i += 256) rcur[i] = 0;
    __syncthreads();
    for (int i = s + t; i < e; i += 256) {
        int2 en = binned[i];
        int rl = en.x >> 18;
        int c  = en.x & 0x3FFFF;
        int off = atomicAdd(&rcur[rl], 1);
        if (off < ELLW) {
            ell[((size_t)(b * 1024 + rl)) * ELLW + off] = make_int2(c, en.y);
        } else {
            int p = atomicAdd(ovcnt, 1);
            if (p < OVCAP) ovbuf[p] = make_int4(b * 1024 + rl, c, en.y, 0);
        }
    }
}

// ---- fused layer v3 (ELL): block = 32 rows; wave owns rows wv*8..wv*8+7.
// Phase 1 is BRANCH-FREE straight-line code: per row, 4 independent ell
// loads (already in regs from previous iteration) -> 4 independent uint4
// gathers (32 lines in flight/wave, 2x v3) -> fma -> fold -> LDS. Next row's
// ell loads issue BEFORE the fma/fold, so the compiler emits counted
// vmcnt(4) waits and the ell latency hides under fold (round-4 lesson:
// static schedule or nothing). No row_ptr chain at all. Dummy slots:
// col=0,val=0 -> gather row 0 (L1-hot), fma adds 0.
// Overflow COO (~40 entries) added to sLE by wave 0 between barriers.
// Phase 2: mdense MFMA from LDS (LE never touches HBM). Eb ping-pong. ----
__global__ __launch_bounds__(256) void k_layer(const int2* __restrict__ ell,
                                               const int4* __restrict__ ovbuf,
                                               const int* __restrict__ ovcnt,
                                               const ushort_t* __restrict__ Eb_in,
                                               float* __restrict__ E,
                                               ushort_t* __restrict__ Eb_out,
                                               const ushort_t* __restrict__ Wfrag,
                                               const float* __restrict__ bsum,
                                               int layer) {
    __shared__ float sLE[32][68];
    __shared__ float sE [32][68];

    int t    = threadIdx.x;
    int wv   = t >> 6;
    int lane = t & 63;
    int oct  = lane >> 3;
    int d8   = (lane & 7) * 8;
    int hl   = lane >> 4;
    int l16  = lane & 15;
    int r0   = blockIdx.x << 5;

    // ---- E-row prefetch into LDS (overlaps with spmm gathers below) ----
    {
        int lr = t >> 3;
        int dm = (t & 7) * 8;
        int gr = r0 + lr;
        float4 va = make_float4(0.f, 0.f, 0.f, 0.f), vb = va;
        if (gr < NN) {
            const float4* p = (const float4*)(E + (size_t)gr * DD + dm);
            va = p[0]; vb = p[1];
        }
        *(float4*)&sE[lr][dm]     = va;
        *(float4*)&sE[lr][dm + 4] = vb;
    }

    // ---- phase 1: ELL spmm, 8 rows per wave, 1-row-ahead pipelined ----
    int baseRow = r0 + wv * 8;                       // max 150015 < ELLROWS
    int2 pv[4];
#pragma unroll
    for (int v = 0; v < 4; v++)
        pv[v] = ell[(size_t)baseRow * ELLW + v * 8 + oct];

#pragma unroll
    for (int sub = 0; sub < 8; sub++) {
        // gathers for current row (pv already in regs -> issue immediately)
        uint4 q[4];
#pragma unroll
        for (int v = 0; v < 4; v++)
            q[v] = *(const uint4*)(Eb_in + ((size_t)(unsigned)pv[v].x << 6) + d8);
        // issue next row's ell loads (independent; counted-vmcnt after q)
        int2 pvn[4];
        if (sub < 7) {
#pragma unroll
            for (int v = 0; v < 4; v++)
                pvn[v] = ell[(size_t)(baseRow + sub + 1) * ELLW + v * 8 + oct];
        }
        // consume gathers (compiler: s_waitcnt vmcnt(4) -> waits q only)
        float acc[8];
#pragma unroll
        for (int k = 0; k < 8; k++) acc[k] = 0.f;
#pragma unroll
        for (int v = 0; v < 4; v++) {
            float w = __int_as_float(pv[v].y);
            acc[0] = fmaf(w, __uint_as_float(q[v].x << 16),         acc[0]);
            acc[1] = fmaf(w, __uint_as_float(q[v].x & 0xffff0000u), acc[1]);
            acc[2] = fmaf(w, __uint_as_float(q[v].y << 16),         acc[2]);
            acc[3] = fmaf(w, __uint_as_float(q[v].y & 0xffff0000u), acc[3]);
            acc[4] = fmaf(w, __uint_as_float(q[v].z << 16),         acc[4]);
            acc[5] = fmaf(w, __uint_as_float(q[v].z & 0xffff0000u), acc[5]);
            acc[6] = fmaf(w, __uint_as_float(q[v].w << 16),         acc[6]);
            acc[7] = fmaf(w, __uint_as_float(q[v].w & 0xffff0000u), acc[7]);
        }
        // fold octs (overlaps pvn flight) + store LE row to LDS
#pragma unroll
        for (int m = 8; m < 64; m <<= 1)
#pragma unroll
            for (int k = 0; k < 8; k++) acc[k] += __shfl_xor(acc[k], m, 64);
        if (oct == 0) {
            int lr = wv * 8 + sub;
            *(float4*)&sLE[lr][d8]     = make_float4(acc[0], acc[1], acc[2], acc[3]);
            *(float4*)&sLE[lr][d8 + 4] = make_float4(acc[4], acc[5], acc[6], acc[7]);
        }
#pragma unroll
        for (int v = 0; v < 4; v++) pv[v] = pvn[v];
    }
    __syncthreads();

    // ---- overflow COO: wave 0 scans the tiny list (expected ~40 entries) ----
    {
        int n = *ovcnt;
        n = (n < OVCAP) ? n : OVCAP;
        if (wv == 0) {
            for (int i = 0; i < n; i++) {
                int4 ov = ovbuf[i];
                if ((unsigned)(ov.x - r0) < 32u) {
                    float w = __int_as_float(ov.z);
                    sLE[ov.x - r0][lane] += w * bf2f(Eb_in[(size_t)ov.y * DD + lane]);
                }
            }
        }
    }
    __syncthreads();

    // ---- phase 2: dense. wave -> (rt = wv&1, jts = {2*(wv>>1), 2*(wv>>1)+1}) ----
    int rt = wv & 1;
    int j0w = wv >> 1;                      // jt pair index
    int jtA = 2 * j0w, jtB = 2 * j0w + 1;
    const uint4* wb = (const uint4*)(Wfrag + (size_t)layer * 8192);
    float bsA = bsum[layer * 64 + jtA * 16 + l16];
    float bsB = bsum[layer * 64 + jtB * 16 + l16];

    f32x4 accA = (f32x4){0.f, 0.f, 0.f, 0.f};
    f32x4 accB = (f32x4){0.f, 0.f, 0.f, 0.f};
    int lrow = rt * 16 + l16;

#pragma unroll
    for (int sh = 0; sh < 2; sh++) {
        bf16x8 w1a, w1b, w2a, w2b;
        {
            uint4 qa = wb[(sh * 4 + jtA) * 64 + lane];
            uint4 qb = wb[(sh * 4 + jtB) * 64 + lane];
            uint4 qc = wb[((2 + sh) * 4 + jtA) * 64 + lane];
            uint4 qd = wb[((2 + sh) * 4 + jtB) * 64 + lane];
            __builtin_memcpy(&w1a, &qa, 16);
            __builtin_memcpy(&w1b, &qb, 16);
            __builtin_memcpy(&w2a, &qc, 16);
            __builtin_memcpy(&w2b, &qd, 16);
        }
        const float* pl = &sLE[lrow][sh * 32 + hl * 8];
        const float* pe = &sE [lrow][sh * 32 + hl * 8];
        float4 l0 = *(const float4*)pl, l1 = *(const float4*)(pl + 4);
        float4 e0 = *(const float4*)pe, e1 = *(const float4*)(pe + 4);
        float le[8] = {l0.x, l0.y, l0.z, l0.w, l1.x, l1.y, l1.z, l1.w};
        float ee[8] = {e0.x, e0.y, e0.z, e0.w, e1.x, e1.y, e1.z, e1.w};
        unsigned int u1h[4], u1l[4], u2h[4], u2l[4];
#pragma unroll
        for (int d = 0; d < 4; d++) {
            float s0 = le[2*d]   + ee[2*d];
            float s1 = le[2*d+1] + ee[2*d+1];
            float m0 = le[2*d]   * ee[2*d];
            float m1 = le[2*d+1] * ee[2*d+1];
            asm("v_cvt_pk_bf16_f32 %0, %1, %2" : "=v"(u1h[d]) : "v"(s0), "v"(s1));
            asm("v_cvt_pk_bf16_f32 %0, %1, %2" : "=v"(u2h[d]) : "v"(m0), "v"(m1));
            float s0r = s0 - __uint_as_float(u1h[d] << 16);
            float s1r = s1 - __uint_as_float(u1h[d] & 0xffff0000u);
            float m0r = m0 - __uint_as_float(u2h[d] << 16);
            float m1r = m1 - __uint_as_float(u2h[d] & 0xffff0000u);
            asm("v_cvt_pk_bf16_f32 %0, %1, %2" : "=v"(u1l[d]) : "v"(s0r), "v"(s1r));
            asm("v_cvt_pk_bf16_f32 %0, %1, %2" : "=v"(u2l[d]) : "v"(m0r), "v"(m1r));
        }
        bf16x8 p1h, p1l, p2h, p2l;
        __builtin_memcpy(&p1h, u1h, 16);
        __builtin_memcpy(&p1l, u1l, 16);
        __builtin_memcpy(&p2h, u2h, 16);
        __builtin_memcpy(&p2l, u2l, 16);

        accA = __builtin_amdgcn_mfma_f32_16x16x32_bf16(p1h, w1a, accA, 0, 0, 0);
        accA = __builtin_amdgcn_mfma_f32_16x16x32_bf16(p1l, w1a, accA, 0, 0, 0);
        accA = __builtin_amdgcn_mfma_f32_16x16x32_bf16(p2h, w2a, accA, 0, 0, 0);
        accA = __builtin_amdgcn_mfma_f32_16x16x32_bf16(p2l, w2a, accA, 0, 0, 0);
        accB = __builtin_amdgcn_mfma_f32_16x16x32_bf16(p1h, w1b, accB, 0, 0, 0);
        accB = __builtin_amdgcn_mfma_f32_16x16x32_bf16(p1l, w1b, accB, 0, 0, 0);
        accB = __builtin_amdgcn_mfma_f32_16x16x32_bf16(p2h, w2b, accB, 0, 0, 0);
        accB = __builtin_amdgcn_mfma_f32_16x16x32_bf16(p2l, w2b, accB, 0, 0, 0);
    }

    // epilogue: bias + leaky relu; C/D layout col=lane&15, row=(lane>>4)*4+g
#pragma unroll
    for (int g = 0; g < 4; g++) {
        int r = r0 + rt * 16 + hl * 4 + g;
        if (r < NN) {
            float hA = accA[g] + bsA; hA = (hA >= 0.f) ? hA : 0.2f * hA;
            float hB = accB[g] + bsB; hB = (hB >= 0.f) ? hB : 0.2f * hB;
            E[(size_t)r * DD + jtA * 16 + l16] = hA;
            E[(size_t)r * DD + jtB * 16 + l16] = hB;
            Eb_out[(size_t)r * DD + jtA * 16 + l16] = f2bf(hA);
            Eb_out[(size_t)r * DD + jtB * 16 + l16] = f2bf(hB);
        }
    }
}

static __device__ __forceinline__ int rid_to_node(int rid,
                                                  const int* users, const int* pos, const int* neg) {
    if (rid < BB)      return users[rid] - 1;
    if (rid < 2 * BB)  return N_USERC + pos[rid - BB] - 1;
    return N_USERC + neg[rid - 2 * BB] - 1;
}

// ---- slice 0 of output: raw initial embedding (fp32) of gathered rows ----
__global__ __launch_bounds__(256) void k_outslice0(const float* __restrict__ E,
                                                   const int* __restrict__ users,
                                                   const int* __restrict__ pos,
                                                   const int* __restrict__ neg,
                                                   float* __restrict__ out) {
    int rid  = blockIdx.x * 4 + (threadIdx.x >> 6);
    int lane = threadIdx.x & 63;
    if (rid >= NRID) return;
    int node = rid_to_node(rid, users, pos, neg);
    out[(size_t)rid * 256 + lane] = E[(size_t)node * DD + lane];
}

// ---- slice l+1: normalized current E of gathered rows (fp32) ----
__global__ __launch_bounds__(256) void k_outnorm(const float* __restrict__ E,
                                                 const int* __restrict__ users,
                                                 const int* __restrict__ pos,
                                                 const int* __restrict__ neg,
                                                 float* __restrict__ out,
                                                 int cbase) {
    int rid  = blockIdx.x * 4 + (threadIdx.x >> 6);
    int lane = threadIdx.x & 63;
    if (rid >= NRID) return;
    int node = rid_to_node(rid, users, pos, neg);
    float v = E[(size_t)node * DD + lane];
    float p2 = v * v;
    for (int m = 1; m < 64; m <<= 1) p2 += __shfl_xor(p2, m, 64);
    float nr = fmaxf(sqrtf(p2), 1e-12f);
    out[(size_t)rid * 256 + cbase + lane] = v / nr;
}

extern "C" void kernel_launch(void* const* d_in, const int* in_sizes, int n_in,
                              void* d_out, int out_size, void* d_ws, size_t ws_size,
                              hipStream_t stream) {
    const void* ue   = d_in[0];
    const void* ie   = d_in[1];
    const void* ev   = d_in[2];
    const void* W1   = d_in[3];
    const void* b1   = d_in[4];
    const void* W2   = d_in[5];
    const void* b2   = d_in[6];
    const int*  ei   = (const int*)d_in[7];
    const int*  usr  = (const int*)d_in[8];
    const int*  posi = (const int*)d_in[9];
    const int*  negi = (const int*)d_in[10];
    float*      out  = (float*)d_out;

    const int* rows = ei;
    const int* cols = ei + NNZC;

    // workspace carve — ~116 MB (Eb0 aliases binned: dead after phaseB; ELL
    // replaces ep+row_ptr; Eb1 slot sized to actual 19.2 MB need)
    char* w = (char*)d_ws;
    float*  E         = (float*)w;  w += (size_t)NN * DD * 4;        // 38.40 MB
    ushort_t* Eb1     = (ushort_t*)w; w += (size_t)NN * DD * 2;      // 19.20 MB
    int2*   binned    = (int2*)w;   w += (size_t)NNZC * 8;           // 19.20 MB
    ushort_t* Eb0     = (ushort_t*)binned;                           // alias
    int2*   ell       = (int2*)w;   w += (size_t)ELLROWS * ELLW * 8; // 38.54 MB
    int4*   ovbuf     = (int4*)w;   w += (size_t)OVCAP * 16;         // 0.52 MB
    int*    ovcnt     = (int*)w;    w += 256;
    int*    gbase     = (int*)w;    w += 1024;
    int*    gcursor   = (int*)w;    w += 1024;
    int*    bucket_cnt= (int*)w;    w += 1024;
    int*    flag      = (int*)w;    w += 256;
    ushort_t* Wfrag   = (ushort_t*)w; w += 49152;                    // 3*4*4*64*8 bf16
    float*  bsum      = (float*)w;  w += 768;                        // 3*64 fp32

    k_sniffzb<<<1, 256, 0, stream>>>((const unsigned int*)ue, flag, bucket_cnt);
    k_zell<<<NZBLK, 256, 0, stream>>>((int4*)ell, ovcnt);
    k_wprep<<<97, 256, 0, stream>>>(W1, W2, b1, b2, flag, Wfrag, bsum);
    k_bhist<<<NABLK, 256, 0, stream>>>(rows, bucket_cnt);
    k_bscan<<<1, 256, 0, stream>>>(bucket_cnt, gbase, gcursor);
    k_phaseA<<<NABLK, 256, 0, stream>>>(rows, cols, ev, flag, gcursor, binned);
    k_phaseB<<<NBKT, 256, 0, stream>>>(gbase, binned, ell, ovbuf, ovcnt);
    k_init2<<<37500, 256, 0, stream>>>(ue, ie, flag, E, Eb0);   // after phaseB: binned dead

    k_outslice0<<<3072, 256, 0, stream>>>(E, usr, posi, negi, out);

    for (int l = 0; l < NLAYER; l++) {
        const ushort_t* ebi = (l & 1) ? Eb1 : Eb0;
        ushort_t*       ebo = (l & 1) ? Eb0 : Eb1;
        k_layer<<<NTILE, 256, 0, stream>>>(ell, ovbuf, ovcnt, ebi, E, ebo, Wfrag, bsum, l);
        k_outnorm<<<3072, 256, 0, stream>>>(E, usr, posi, negi, out, 64 * (l + 1));
    }
}